// Round 19
// baseline (1694.742 us; speedup 1.0000x reference)
//
#include <hip/hip_runtime.h>
#include <math.h>

#define H 512
#define V 5000
#define BB 128
#define SS 64
#define TT 52

typedef __attribute__((ext_vector_type(8))) short bf16x8;
typedef __attribute__((ext_vector_type(4))) float f32x4;
typedef __attribute__((ext_vector_type(2))) float f32x2;

__device__ __forceinline__ unsigned short f2b(float f) {
    unsigned u = __float_as_uint(f);
    return (unsigned short)((u + 0x7fffu + ((u >> 16) & 1u)) >> 16);
}
__device__ __forceinline__ float b2f(unsigned short u) {
    return __uint_as_float((unsigned)u << 16);
}
__device__ __forceinline__ float ftanh(float x) {
    return 1.f - 2.f / (1.f + __expf(2.f * x));
}
__device__ __forceinline__ float fsig(float x) {
    return 1.f / (1.f + __expf(-x));
}
__device__ __forceinline__ unsigned char f2fp8(float f) {
    return (unsigned char)__builtin_amdgcn_cvt_pk_fp8_f32(f, f, 0, 0);
}

// ---------------------------------------------------------------------------
// prep: Whb [2560][512] = [Wa ; W_hh], Wxb [2048][512] = W_ih[:, :512],
// Wc [2048][512] = W_ih[:, 512:], bbig = [ba ; b_ih+b_hh], bf16 Ua/Wout/enc/
// emb, hbuf = f2b(h0), cbuf = c0.  (No flags, no xall: kernel-boundary sync.)
// ---------------------------------------------------------------------------
__global__ __launch_bounds__(256)
void prep_w(const float* __restrict__ Wa, const float* __restrict__ Whh,
            const float* __restrict__ Wih,
            const float* __restrict__ ba, const float* __restrict__ bih,
            const float* __restrict__ bhh,
            const float* __restrict__ Ua, const float* __restrict__ Wout,
            const float* __restrict__ enc, const float* __restrict__ emb,
            const float* __restrict__ h0, const float* __restrict__ c0,
            unsigned short* __restrict__ Whb, unsigned short* __restrict__ Wxb,
            unsigned short* __restrict__ Wc,
            unsigned short* __restrict__ Uab, unsigned short* __restrict__ Woutb,
            unsigned short* __restrict__ encb, unsigned short* __restrict__ embb,
            unsigned short* __restrict__ hbuf, float* __restrict__ cbuf,
            float* __restrict__ bbig)
{
    const int stride = gridDim.x * blockDim.x;
    const int t0 = blockIdx.x * blockDim.x + threadIdx.x;
    for (int idx = t0; idx < 2560 * 512; idx += stride) {
        const int j = idx >> 9, k = idx & 511;
        Whb[idx] = f2b((j < H) ? Wa[j * H + k] : Whh[(j - H) * H + k]);
    }
    for (int idx = t0; idx < 2048 * 512; idx += stride) {
        const int n = idx >> 9, k = idx & 511;
        Wxb[idx] = f2b(Wih[n * 2 * H + k]);
        Wc[idx]  = f2b(Wih[n * 2 * H + H + k]);
    }
    for (int idx = t0; idx < 512 * 512; idx += stride)   Uab[idx]   = f2b(Ua[idx]);
    for (int idx = t0; idx < V * 512; idx += stride)     Woutb[idx] = f2b(Wout[idx]);
    for (int idx = t0; idx < BB * SS * H; idx += stride) encb[idx]  = f2b(enc[idx]);
    for (int idx = t0; idx < 5120 * 512; idx += stride)
        embb[idx] = (idx < V * 512) ? f2b(emb[idx]) : (unsigned short)0;
    for (int idx = t0; idx < BB * H; idx += stride) {
        hbuf[idx] = f2b(h0[idx]);
        cbuf[idx] = c0[idx];
    }
    for (int j = t0; j < 2560; j += stride)
        bbig[j] = (j < H) ? ba[j] : bih[j - H] + bhh[j - H];
}

// ---------------------------------------------------------------------------
// bf16 MFMA NT-GEMM, K=512. OUT_MODE: 0=f32 (+PERMUTE r=t*B+b -> b*T+t),
// 1=bf16, 2=fp8. Used for keysb, encW8, embW, per-step Y, logits.
// ---------------------------------------------------------------------------
template<int OUT_MODE, int PERMUTE>
__global__ __launch_bounds__(256, 2)
void gemm_mfma(const unsigned short* __restrict__ A,
               const unsigned short* __restrict__ B,
               const float* __restrict__ bias,
               float* __restrict__ Cf, unsigned short* __restrict__ Cb,
               unsigned char* __restrict__ C8,
               int M, int N)
{
    __shared__ unsigned short As[128][72];
    __shared__ unsigned short Bs[128][72];
    const int tid = threadIdx.x;
    const int m0 = blockIdx.y * 128, n0 = blockIdx.x * 128;
    const int lane = tid & 63, wv = tid >> 6;
    const int qm = (wv >> 1) * 64, qn = (wv & 1) * 64;
    const int fr = lane & 15, fg = lane >> 4;
    f32x4 acc[4][4];
#pragma unroll
    for (int i = 0; i < 4; ++i)
#pragma unroll
        for (int j = 0; j < 4; ++j) acc[i][j] = (f32x4){0.f, 0.f, 0.f, 0.f};

    const int srow = tid >> 3, sc = (tid & 7) * 8;
    for (int k0 = 0; k0 < H; k0 += 64) {
#pragma unroll
        for (int u = 0; u < 4; ++u) {
            const int row = srow + u * 32;
            *(uint4*)&As[row][sc] = *(const uint4*)&A[(size_t)(m0 + row) * H + k0 + sc];
            int nr = n0 + row; if (nr > N - 1) nr = N - 1;
            *(uint4*)&Bs[row][sc] = *(const uint4*)&B[(size_t)nr * H + k0 + sc];
        }
        __syncthreads();
#pragma unroll
        for (int ks = 0; ks < 2; ++ks) {
            const int kk = ks * 32 + fg * 8;
            bf16x8 av[4], bv[4];
#pragma unroll
            for (int i = 0; i < 4; ++i) {
                av[i] = *(const bf16x8*)&As[qm + i * 16 + fr][kk];
                bv[i] = *(const bf16x8*)&Bs[qn + i * 16 + fr][kk];
            }
#pragma unroll
            for (int i = 0; i < 4; ++i)
#pragma unroll
                for (int j = 0; j < 4; ++j)
                    acc[i][j] = __builtin_amdgcn_mfma_f32_16x16x32_bf16(av[i], bv[j], acc[i][j], 0, 0, 0);
        }
        __syncthreads();
    }
#pragma unroll
    for (int i = 0; i < 4; ++i) {
        const int r0 = m0 + qm + i * 16 + fg * 4;
#pragma unroll
        for (int j = 0; j < 4; ++j) {
            const int col = n0 + qn + j * 16 + fr;
            if (col < N) {
                const float bi = bias ? bias[col] : 0.f;
#pragma unroll
                for (int v = 0; v < 4; ++v) {
                    const int r = r0 + v;
                    const float val = acc[i][j][v] + bi;
                    if (OUT_MODE == 1) Cb[(size_t)r * N + col] = f2b(val);
                    else if (OUT_MODE == 2) C8[(size_t)r * N + col] = f2fp8(val);
                    else {
                        const size_t orow = PERMUTE ? ((size_t)(r & (BB - 1)) * TT + (r >> 7))
                                                    : (size_t)r;
                        Cf[orow * (size_t)N + col] = val;
                    }
                }
            }
        }
    }
}

// ---------------------------------------------------------------------------
// Per-step S2: one block per batch. Kernel boundary = the sync (plain cached
// memory; HW guarantees prior-launch writes visible). scores -> softmax ->
// gates = encW8-sum + Y[512:] + embW[token] -> LSTM; h -> hbuf, hallb.
// ---------------------------------------------------------------------------
__global__ __launch_bounds__(256)
void step2(int t, const int* __restrict__ tgt,
           const unsigned short* __restrict__ keysb,
           const unsigned char* __restrict__ encW8,
           const unsigned short* __restrict__ embW,
           const float* __restrict__ Va, const float* __restrict__ bv,
           const float* __restrict__ Ybuf,
           float* __restrict__ cbuf, unsigned short* __restrict__ hbuf,
           unsigned short* __restrict__ hallb, float* __restrict__ attn,
           float* __restrict__ out_h, float* __restrict__ out_c)
{
    __shared__ float qa_s[H];
    __shared__ float va_s[H];
    __shared__ float part[SS][4];
    __shared__ float wbuf[SS];
    __shared__ float gbuf[4 * H];

    const int tid = threadIdx.x;
    const int b = blockIdx.x;
    const float* yrow = Ybuf + (size_t)b * 2560;

    qa_s[tid]       = yrow[tid];
    qa_s[tid + 256] = yrow[tid + 256];
    va_s[tid]       = Va[tid];
    va_s[tid + 256] = Va[tid + 256];
    __syncthreads();

    // scores (2-way ILP tanh chain, bf16x8 keys)
    {
        const int s = tid >> 2, q = tid & 3;
        const unsigned short* kp = keysb + ((size_t)b * SS + s) * H + q * 128;
        const float* qp = qa_s + q * 128;
        const float* vp = va_s + q * 128;
        float a2 = 0.f, a2b = 0.f;
#pragma unroll
        for (int i8 = 0; i8 < 16; ++i8) {
            bf16x8 kv = *(const bf16x8*)&kp[i8 * 8];
#pragma unroll
            for (int u = 0; u < 8; u += 2) {
                const int i = i8 * 8 + u;
                a2  += ftanh(qp[i]     + b2f((unsigned short)kv[u]))     * vp[i];
                a2b += ftanh(qp[i + 1] + b2f((unsigned short)kv[u + 1])) * vp[i + 1];
            }
        }
        part[s][q] = a2 + a2b;
    }
    __syncthreads();
    if (tid < 64) {
        float sc = part[tid][0] + part[tid][1] + part[tid][2] + part[tid][3] + bv[0];
        float m = sc;
        for (int o = 32; o; o >>= 1) m = fmaxf(m, __shfl_xor(m, o));
        const float e = __expf(sc - m);
        float ss = e;
        for (int o = 32; o; o >>= 1) ss += __shfl_xor(ss, o);
        const float w = e / ss;
        wbuf[tid] = w;
        attn[((size_t)b * TT + t) * SS + tid] = w;
    }
    __syncthreads();

    // gates = encW8-weighted-sum + Y gate cols + embW[token] (x-part)
    {
        const int tok = (t == 0) ? 0 : tgt[b * TT + t - 1];
        float gc[8] = {0.f, 0.f, 0.f, 0.f, 0.f, 0.f, 0.f, 0.f};
        const unsigned char* ew = encW8 + (size_t)b * SS * 2048 + tid * 8;
#pragma unroll 8
        for (int s2 = 0; s2 < SS; ++s2) {
            const float w2 = wbuf[s2];
            const uint2 u = *(const uint2*)(ew + (size_t)s2 * 2048);
            const f32x2 e01 = __builtin_amdgcn_cvt_pk_f32_fp8(u.x, 0);
            const f32x2 e23 = __builtin_amdgcn_cvt_pk_f32_fp8(u.x, 1);
            const f32x2 e45 = __builtin_amdgcn_cvt_pk_f32_fp8(u.y, 0);
            const f32x2 e67 = __builtin_amdgcn_cvt_pk_f32_fp8(u.y, 1);
            gc[0] += w2 * e01[0]; gc[1] += w2 * e01[1];
            gc[2] += w2 * e23[0]; gc[3] += w2 * e23[1];
            gc[4] += w2 * e45[0]; gc[5] += w2 * e45[1];
            gc[6] += w2 * e67[0]; gc[7] += w2 * e67[1];
        }
        const f32x4 y0 = *(const f32x4*)&yrow[512 + tid * 8];
        const f32x4 y1 = *(const f32x4*)&yrow[512 + tid * 8 + 4];
        const bf16x8 xg = *(const bf16x8*)&embW[(size_t)tok * 2048 + tid * 8];
#pragma unroll
        for (int i = 0; i < 4; ++i) {
            gbuf[tid * 8 + i]     = gc[i]     + y0[i] + b2f((unsigned short)xg[i]);
            gbuf[tid * 8 + 4 + i] = gc[4 + i] + y1[i] + b2f((unsigned short)xg[4 + i]);
        }
    }
    __syncthreads();

    // LSTM: cells 2*tid, 2*tid+1
    {
        const int last = (t == TT - 1);
        unsigned hpack = 0;
        float hn2[2], cn2[2];
#pragma unroll
        for (int u = 0; u < 2; ++u) {
            const int j = tid * 2 + u;
            const float ig  = gbuf[j];
            const float fgt = gbuf[512 + j];
            const float gg  = gbuf[1024 + j];
            const float og  = gbuf[1536 + j];
            const float co  = cbuf[(size_t)b * H + j];
            const float cn = fsig(fgt) * co + fsig(ig) * ftanh(gg);
            const float hn = fsig(og) * ftanh(cn);
            cbuf[(size_t)b * H + j] = cn;
            hn2[u] = hn; cn2[u] = cn;
            hpack |= ((unsigned)f2b(hn)) << (16 * u);
        }
        *(unsigned*)&hbuf[(size_t)b * H + tid * 2] = hpack;
        *(unsigned*)&hallb[((size_t)t * BB + b) * H + tid * 2] = hpack;
        if (last) {
#pragma unroll
            for (int u = 0; u < 2; ++u) {
                out_h[(size_t)b * H + tid * 2 + u] = hn2[u];
                out_c[(size_t)b * H + tid * 2 + u] = cn2[u];
            }
        }
    }
}

// ---------------------------------------------------------------------------
// Online (2-pass) log-softmax over each row of 5000 logits.
// ---------------------------------------------------------------------------
__global__ __launch_bounds__(256)
void logsoftmax_rows(float* __restrict__ P)
{
    __shared__ float redm[256], reds[256];
    float* p = P + (size_t)blockIdx.x * V;
    const int tid = threadIdx.x;
    float m = -1e30f, ssum = 0.f;
    for (int i = tid; i < V; i += 256) {
        const float v = p[i];
        if (v > m) { ssum = ssum * __expf(m - v) + 1.f; m = v; }
        else       ssum += __expf(v - m);
    }
    redm[tid] = m; reds[tid] = ssum;
    __syncthreads();
    for (int sft = 128; sft; sft >>= 1) {
        if (tid < sft) {
            const float m2 = redm[tid + sft], s2 = reds[tid + sft];
            const float mm = fmaxf(redm[tid], m2);
            reds[tid] = reds[tid] * __expf(redm[tid] - mm) + s2 * __expf(m2 - mm);
            redm[tid] = mm;
        }
        __syncthreads();
    }
    const float lse = redm[0] + __logf(reds[0]);
    for (int i = tid; i < V; i += 256) p[i] -= lse;
}

// ---------------------------------------------------------------------------
extern "C" void kernel_launch(void* const* d_in, const int* in_sizes, int n_in,
                              void* d_out, int out_size, void* d_ws, size_t ws_size,
                              hipStream_t stream)
{
    (void)in_sizes; (void)n_in; (void)out_size; (void)ws_size;
    const float* enc  = (const float*)d_in[0];
    const float* h0   = (const float*)d_in[1];
    const float* c0   = (const float*)d_in[2];
    const int*   tgt  = (const int*)  d_in[3];
    const float* emb  = (const float*)d_in[4];
    const float* Wa   = (const float*)d_in[5];
    const float* ba   = (const float*)d_in[6];
    const float* Ua   = (const float*)d_in[7];
    const float* bu   = (const float*)d_in[8];
    const float* Va   = (const float*)d_in[9];
    const float* bv   = (const float*)d_in[10];
    const float* Wih  = (const float*)d_in[11];
    const float* Whh  = (const float*)d_in[12];
    const float* bih  = (const float*)d_in[13];
    const float* bhh  = (const float*)d_in[14];
    const float* Wout = (const float*)d_in[15];
    const float* bout = (const float*)d_in[16];

    float* ws = (float*)d_ws;
    float* bbig = ws;                                      // 2,560 f32
    float* Ybuf = bbig + 2560;                             // 327,680 f32
    float* cbuf = Ybuf + 327680;                           // 65,536 f32
    unsigned short* Whb   = (unsigned short*)(cbuf + 65536);   // 1,310,720 u16
    unsigned short* Wxb   = Whb + 1310720;                 // 1,048,576
    unsigned short* Wc    = Wxb + 1048576;                 // 1,048,576
    unsigned short* Uab   = Wc + 1048576;                  // 262,144
    unsigned short* Woutb = Uab + 262144;                  // 2,560,000
    unsigned short* encb  = Woutb + 2560000;               // 4,194,304
    unsigned short* embb  = encb + 4194304;                // 2,621,440 (5120 rows)
    unsigned short* embW  = embb + 2621440;                // 10,485,760 (5120x2048)
    unsigned short* keysb = embW + 10485760;               // 4,194,304
    unsigned short* hallb = keysb + 4194304;               // 3,407,872
    unsigned short* hbuf  = hallb + 3407872;               // 65,536
    unsigned char*  encW8 = (unsigned char*)(hbuf + 65536); // 16,777,216 u8

    float* out    = (float*)d_out;
    float* out_h  = out + (size_t)BB * TT * V;
    float* out_c  = out_h + BB * H;
    float* out_at = out_c + BB * H;

    prep_w<<<dim3(2048), dim3(256), 0, stream>>>(
        Wa, Whh, Wih, ba, bih, bhh, Ua, Wout, enc, emb, h0, c0,
        Whb, Wxb, Wc, Uab, Woutb, encb, embb, hbuf, cbuf, bbig);

    // keysb = enc @ Ua^T + bu -> bf16 [8192,512]
    gemm_mfma<1, 0><<<dim3(4, 64), dim3(256), 0, stream>>>(
        encb, Uab, bu, nullptr, keysb, nullptr, BB * SS, H);
    // encW8 = enc @ Wc^T -> fp8 [8192,2048]
    gemm_mfma<2, 0><<<dim3(16, 64), dim3(256), 0, stream>>>(
        encb, Wc, nullptr, nullptr, nullptr, encW8, BB * SS, 2048);
    // embW = emb @ Wx^T -> bf16 [5120,2048]  (vocab-sized x-part, gathered in S2)
    gemm_mfma<1, 0><<<dim3(16, 40), dim3(256), 0, stream>>>(
        embb, Wxb, nullptr, nullptr, embW, nullptr, 5120, 2048);

    // ------------- recurrence: 52 x (S1 GEMM + S2), kernel-boundary sync ----
    for (int t = 0; t < TT; ++t) {
        // S1: Y = h @ Whb^T + bbig   [128, 2560]
        gemm_mfma<0, 0><<<dim3(20, 1), dim3(256), 0, stream>>>(
            hbuf, Whb, bbig, Ybuf, nullptr, nullptr, BB, 2560);
        // S2: attention + gates + LSTM per batch
        step2<<<dim3(BB), dim3(256), 0, stream>>>(
            t, tgt, keysb, encW8, embW, Va, bv, Ybuf, cbuf, hbuf,
            hallb, out_at, out_h, out_c);
    }

    // logits: hallb[6656,512] @ Woutb^T + bout -> out[b,t,:], then log-softmax
    gemm_mfma<0, 1><<<dim3(40, 52), dim3(256), 0, stream>>>(
        hallb, Woutb, bout, out, nullptr, nullptr, TT * BB, V);
    logsoftmax_rows<<<dim3(BB * TT), dim3(256), 0, stream>>>(out);
}